// Round 1
// baseline (229.137 us; speedup 1.0000x reference)
//
#include <hip/hip_runtime.h>
#include <hip/hip_bf16.h>

typedef __bf16 bf16;
typedef __bf16 v8bf __attribute__((ext_vector_type(8)));
typedef float v4f __attribute__((ext_vector_type(4)));

#define HW 4096
#define CH 256
#define KC 32
#define RD 16
#define NB 2
#define BNEPS 1e-5f

// ---------------- workspace byte offsets (total ~48.3 MiB) ----------------
#define OFF_MEAN   0u          // f32 [2][256]
#define OFF_WKB    4096u       // f32 [2][32][256] gate-folded Wk
#define OFF_QT     69632u      // bf16 [2][4096][32]
#define OFF_KT     593920u     // bf16 [2][4096][32]
#define OFF_BS1    1118208u    // bf16 [2][4096][32] pooled b1
#define OFF_BS2    1642496u    // bf16 [2][4096][32] pooled b2
#define OFF_VT     2166784u    // bf16 [2][256][4096] V transposed
#define OFF_B1R    6361088u    // f32 [2][4096][32] raw relu(Wb1 x)
#define OFF_B2R    7409664u    // f32 [2][4096][32]
#define OFF_CTX    8458240u    // f32 [2][4096][256]
#define OFF_PACC   16846848u   // f32 [2048][16][256] split-K partial ctx
#define OFF_PM     50401280u   // f32 [2048*16] running max
#define OFF_PL     50532352u   // f32 [2048*16] running sum

// ---------------- K1: per-(b,c) spatial mean ----------------
__global__ __launch_bounds__(256) void k_mean(const float* __restrict__ x,
                                              float* __restrict__ mean) {
  int bc = blockIdx.x;                       // 0..511
  const float* px = x + (size_t)bc * HW;
  float s = 0.f;
  for (int i = threadIdx.x; i < HW; i += 256) s += px[i];
  __shared__ float red[256];
  red[threadIdx.x] = s; __syncthreads();
  for (int st = 128; st > 0; st >>= 1) {
    if (threadIdx.x < st) red[threadIdx.x] += red[threadIdx.x + st];
    __syncthreads();
  }
  if (threadIdx.x == 0) mean[bc] = red[0] * (1.0f / HW);
}

// ---------------- K2: GatherExcite MLP gate, folded into Wk ----------------
__global__ __launch_bounds__(256) void k_gate(const float* __restrict__ mean,
    const float* __restrict__ gw1, const float* __restrict__ gb1,
    const float* __restrict__ gw2, const float* __restrict__ gb2,
    const float* __restrict__ Wk, float* __restrict__ wkb) {
  int b = blockIdx.x;
  int t = threadIdx.x;                        // = channel c
  __shared__ float ms[CH];
  __shared__ float hid[RD];
  ms[t] = mean[b * CH + t];
  __syncthreads();
  if (t < RD) {
    float a = gb1[t];
    for (int c = 0; c < CH; ++c) a += gw1[t * CH + c] * ms[c];
    hid[t] = fmaxf(a, 0.f);
  }
  __syncthreads();
  float a = gb2[t];
  #pragma unroll
  for (int r = 0; r < RD; ++r) a += gw2[t * RD + r] * hid[r];
  float s = 1.f / (1.f + __expf(-a));         // sigmoid gate for channel t
  for (int kk = 0; kk < KC; ++kk)
    wkb[((size_t)b * KC + kk) * CH + t] = Wk[kk * CH + t] * s;
}

// ---------------- K3: fused 1x1 projections  ----------------
// outputs per spatial position n: q(32) k(32,gated) b1(32,relu) b2(32,relu) v(256)
// grid: b * 128 tiles * 2 output-halves; 32 positions per tile
__global__ __launch_bounds__(256, 2) void k_proj(
    const float* __restrict__ x, const float* __restrict__ Wq,
    const float* __restrict__ wkb, const float* __restrict__ Wb1,
    const float* __restrict__ Wb2, const float* __restrict__ Wv,
    bf16* __restrict__ qt, bf16* __restrict__ kt,
    float* __restrict__ b1r, float* __restrict__ b2r, bf16* __restrict__ vt) {
  __shared__ __align__(16) float xs[CH * 36];
  const int blk  = blockIdx.x;
  const int half = blk & 1;
  const int nn   = (blk >> 1) & 127;
  const int b    = blk >> 8;
  const int n0   = nn * 32;
  const int t    = threadIdx.x;
  // stage x tile [256 ch][32 pos] into LDS (coalesced)
  {
    const int j = t & 31, crow = t >> 5;
    const float* xb = x + ((size_t)b * CH) * HW + n0;
    #pragma unroll
    for (int i = 0; i < 32; ++i) {
      int c = crow + 8 * i;
      xs[c * 36 + j] = xb[(size_t)c * HW + j];
    }
  }
  __syncthreads();
  const int og = t >> 3;                      // 0..31 output group
  const int jg = t & 7;                       // 4 positions each
  const float* wkb_b = wkb + (size_t)b * KC * CH;
  const float* wp[6];
  #pragma unroll
  for (int oo = 0; oo < 6; ++oo) {
    int o = half * 192 + og * 6 + oo;
    const float* w;
    if (o < 32)       w = Wq   + o * CH;
    else if (o < 64)  w = wkb_b + (o - 32) * CH;
    else if (o < 96)  w = Wb1  + (o - 64) * CH;
    else if (o < 128) w = Wb2  + (o - 96) * CH;
    else              w = Wv   + (o - 128) * CH;
    wp[oo] = w;
  }
  float acc[6][4];
  #pragma unroll
  for (int oo = 0; oo < 6; ++oo)
    #pragma unroll
    for (int jj = 0; jj < 4; ++jj) acc[oo][jj] = 0.f;
  for (int c0 = 0; c0 < CH; c0 += 4) {
    v4f xv[4];
    #pragma unroll
    for (int cc = 0; cc < 4; ++cc)
      xv[cc] = *(const v4f*)&xs[(c0 + cc) * 36 + jg * 4];
    #pragma unroll
    for (int oo = 0; oo < 6; ++oo) {
      v4f wv = *(const v4f*)(wp[oo] + c0);
      #pragma unroll
      for (int cc = 0; cc < 4; ++cc)
        #pragma unroll
        for (int jj = 0; jj < 4; ++jj)
          acc[oo][jj] += wv[cc] * xv[cc][jj];
    }
  }
  #pragma unroll
  for (int oo = 0; oo < 6; ++oo) {
    int o = half * 192 + og * 6 + oo;
    #pragma unroll
    for (int jj = 0; jj < 4; ++jj) {
      int n = n0 + jg * 4 + jj;
      size_t nb = (size_t)b * HW + n;
      float v = acc[oo][jj];
      if (o < 32)       qt[nb * KC + o] = (bf16)v;
      else if (o < 64)  kt[nb * KC + (o - 32)] = (bf16)v;
      else if (o < 96)  b1r[nb * KC + (o - 64)] = fmaxf(v, 0.f);
      else if (o < 128) b2r[nb * KC + (o - 96)] = fmaxf(v, 0.f);
      else              vt[((size_t)b * CH + (o - 128)) * HW + n] = (bf16)v;
    }
  }
}

// ---------------- K3b: 1-D 3-tap pool of the bias factors ----------------
__global__ __launch_bounds__(256) void k_pool(const float* __restrict__ b1r,
    const float* __restrict__ b2r, bf16* __restrict__ bs1, bf16* __restrict__ bs2) {
  int i = blockIdx.x * 256 + threadIdx.x;     // (b*HW + n)*KC + k
  int n = (i >> 5) & (HW - 1);
  float a = b1r[i], c = b2r[i];
  if (n > 0)      { a += b1r[i - KC]; c += b2r[i - KC]; }
  if (n < HW - 1) { a += b1r[i + KC]; c += b2r[i + KC]; }
  bs1[i] = (bf16)a;
  bs2[i] = (bf16)c;
}

// ---------------- K4: fused flash attention (bf16 MFMA, split-K=4) ----------------
// one wave per block; 16 query rows x 1024 keys per wave; tiles of 64 keys
__global__ __launch_bounds__(64, 2) void k_attn(
    const bf16* __restrict__ qtg, const bf16* __restrict__ ktg,
    const bf16* __restrict__ bs1g, const bf16* __restrict__ bs2g,
    const bf16* __restrict__ vtg, const float* __restrict__ wgb,
    float* __restrict__ pacc, float* __restrict__ pm, float* __restrict__ pl) {
  __shared__ __align__(16) bf16 plds[16 * 72];
  const int blk = blockIdx.x;
  const int b   = blk >> 10;
  const int rg  = (blk >> 2) & 255;
  const int sp  = blk & 3;
  const int lane = threadIdx.x;
  const int cl = lane & 15;
  const int kh = lane >> 4;
  const float wscale = wgb[0] * (1.f / 9.f);
  const v4f vzero = {0.f, 0.f, 0.f, 0.f};
  // A-fragments (row = lane&15 = query, k = 8*(lane>>4)+j), loaded once
  const size_t qoff = ((size_t)(b * HW + rg * 16 + cl)) * KC + kh * 8;
  const v8bf qf  = *(const v8bf*)(qtg + qoff);
  const v8bf b1f = *(const v8bf*)(bs1g + qoff);
  const bf16* kt = ktg + (size_t)b * HW * KC;
  const bf16* b2 = bs2g + (size_t)b * HW * KC;
  const bf16* vt = vtg + (size_t)b * CH * HW;
  v4f acc[16];
  #pragma unroll
  for (int f = 0; f < 16; ++f) acc[f] = vzero;
  float rmax[4] = {-1e30f, -1e30f, -1e30f, -1e30f};
  float rsum[4] = {0.f, 0.f, 0.f, 0.f};

  for (int tt = 0; tt < 16; ++tt) {
    const int m0 = sp * 1024 + tt * 64;
    v4f sim[4], bia[4];
    #pragma unroll
    for (int cb = 0; cb < 4; ++cb) {
      size_t ko = ((size_t)(m0 + cb * 16 + cl)) * KC + kh * 8;   // B-frag: col=key
      v8bf kf  = *(const v8bf*)(kt + ko);
      v8bf b2f = *(const v8bf*)(b2 + ko);
      sim[cb] = __builtin_amdgcn_mfma_f32_16x16x32_bf16(qf,  kf,  vzero, 0, 0, 0);
      bia[cb] = __builtin_amdgcn_mfma_f32_16x16x32_bf16(b1f, b2f, vzero, 0, 0, 0);
    }
    // C-layout: lane holds rows kh*4+r, col cb*16+cl. Online softmax per row.
    float p[4][4];
    float alpha[4];
    #pragma unroll
    for (int r = 0; r < 4; ++r) {
      float s[4];
      #pragma unroll
      for (int cb = 0; cb < 4; ++cb) {
        float z = wscale * bia[cb][r];
        float bm = 1.f / (1.f + __expf(-z));      // sigmoid(w_gb * pooled/9)
        s[cb] = sim[cb][r] * bm;
      }
      float mx = fmaxf(fmaxf(s[0], s[1]), fmaxf(s[2], s[3]));
      mx = fmaxf(mx, __shfl_xor(mx, 1));
      mx = fmaxf(mx, __shfl_xor(mx, 2));
      mx = fmaxf(mx, __shfl_xor(mx, 4));
      mx = fmaxf(mx, __shfl_xor(mx, 8));
      float nm = fmaxf(rmax[r], mx);
      float al = __expf(rmax[r] - nm);
      float ts = 0.f;
      #pragma unroll
      for (int cb = 0; cb < 4; ++cb) { p[cb][r] = __expf(s[cb] - nm); ts += p[cb][r]; }
      ts += __shfl_xor(ts, 1);
      ts += __shfl_xor(ts, 2);
      ts += __shfl_xor(ts, 4);
      ts += __shfl_xor(ts, 8);
      rsum[r] = rsum[r] * al + ts;
      rmax[r] = nm;
      alpha[r] = al;
    }
    #pragma unroll
    for (int f = 0; f < 16; ++f) {
      acc[f][0] *= alpha[0]; acc[f][1] *= alpha[1];
      acc[f][2] *= alpha[2]; acc[f][3] *= alpha[3];
    }
    // relayout P (C-layout) -> A-fragment via LDS
    __syncthreads();
    #pragma unroll
    for (int cb = 0; cb < 4; ++cb)
      #pragma unroll
      for (int r = 0; r < 4; ++r)
        plds[(kh * 4 + r) * 72 + cb * 16 + cl] = (bf16)p[cb][r];
    __syncthreads();
    const v8bf pa0 = *(const v8bf*)&plds[cl * 72 + kh * 8];
    const v8bf pa1 = *(const v8bf*)&plds[cl * 72 + 32 + kh * 8];
    #pragma unroll
    for (int f = 0; f < 16; ++f) {
      size_t vo = ((size_t)(f * 16 + cl)) * HW + (m0 + kh * 8);  // Vt[c][m]
      v8bf v0 = *(const v8bf*)(vt + vo);
      v8bf v1 = *(const v8bf*)(vt + vo + 32);
      acc[f] = __builtin_amdgcn_mfma_f32_16x16x32_bf16(pa0, v0, acc[f], 0, 0, 0);
      acc[f] = __builtin_amdgcn_mfma_f32_16x16x32_bf16(pa1, v1, acc[f], 0, 0, 0);
    }
  }
  float* po = pacc + (size_t)blk * 16 * CH;
  #pragma unroll
  for (int f = 0; f < 16; ++f)
    #pragma unroll
    for (int r = 0; r < 4; ++r)
      po[(size_t)(kh * 4 + r) * CH + f * 16 + cl] = acc[f][r];
  if (cl == 0) {
    #pragma unroll
    for (int r = 0; r < 4; ++r) {
      pm[blk * 16 + kh * 4 + r] = rmax[r];
      pl[blk * 16 + kh * 4 + r] = rsum[r];
    }
  }
}

// ---------------- K4b: split-K softmax combine ----------------
__global__ __launch_bounds__(256) void k_combine(const float* __restrict__ pacc,
    const float* __restrict__ pm, const float* __restrict__ pl,
    float* __restrict__ ctx) {
  const int r = blockIdx.x * 4 + (threadIdx.x >> 6);   // global row 0..8191
  const int lane = threadIdx.x & 63;
  const int b = r >> 12;
  const int n = r & (HW - 1);
  const int rg = n >> 4, rl = n & 15;
  const int wg0 = b * 1024 + rg * 4;
  float mv[4], w[4];
  float M = -1e30f;
  #pragma unroll
  for (int s = 0; s < 4; ++s) { mv[s] = pm[(wg0 + s) * 16 + rl]; M = fmaxf(M, mv[s]); }
  float den = 0.f;
  #pragma unroll
  for (int s = 0; s < 4; ++s) { w[s] = __expf(mv[s] - M); den += w[s] * pl[(wg0 + s) * 16 + rl]; }
  const float inv = 1.f / den;
  #pragma unroll
  for (int c0 = 0; c0 < CH; c0 += 64) {
    int c = c0 + lane;
    float a = 0.f;
    #pragma unroll
    for (int s = 0; s < 4; ++s)
      a += w[s] * pacc[((size_t)(wg0 + s) * 16 + rl) * CH + c];
    ctx[(size_t)r * CH + c] = a * inv;
  }
}

// ---------------- K5: output 1x1 conv + BN + ReLU + residual ----------------
__global__ __launch_bounds__(256, 2) void k_out(
    const float* __restrict__ ctx, const float* __restrict__ Wo,
    const float* __restrict__ bns, const float* __restrict__ bnb,
    const float* __restrict__ bnm, const float* __restrict__ bnv,
    const float* __restrict__ gamma, const float* __restrict__ x,
    float* __restrict__ out) {
  __shared__ __align__(16) float cs[CH * 36];
  const int blk  = blockIdx.x;
  const int half = blk & 1;
  const int nn   = (blk >> 1) & 127;
  const int b    = blk >> 8;
  const int n0   = nn * 32;
  const int t    = threadIdx.x;
  for (int i = t; i < 32 * 256; i += 256) {
    int j = i >> 8, c = i & 255;
    cs[c * 36 + j] = ctx[((size_t)b * HW + n0 + j) * CH + c];
  }
  __syncthreads();
  const int og = t >> 3, jg = t & 7;
  float acc[4][4];
  #pragma unroll
  for (int oo = 0; oo < 4; ++oo)
    #pragma unroll
    for (int jj = 0; jj < 4; ++jj) acc[oo][jj] = 0.f;
  const int o0 = half * 128 + og * 4;
  for (int c0 = 0; c0 < CH; c0 += 4) {
    v4f xv[4];
    #pragma unroll
    for (int cc = 0; cc < 4; ++cc)
      xv[cc] = *(const v4f*)&cs[(c0 + cc) * 36 + jg * 4];
    #pragma unroll
    for (int oo = 0; oo < 4; ++oo) {
      v4f wv = *(const v4f*)&Wo[(o0 + oo) * CH + c0];
      #pragma unroll
      for (int cc = 0; cc < 4; ++cc)
        #pragma unroll
        for (int jj = 0; jj < 4; ++jj)
          acc[oo][jj] += wv[cc] * xv[cc][jj];
    }
  }
  const float g = gamma[0];
  #pragma unroll
  for (int oo = 0; oo < 4; ++oo) {
    int o = o0 + oo;
    float isc = bns[o] / sqrtf(bnv[o] + BNEPS);
    float mu = bnm[o], bb = bnb[o];
    #pragma unroll
    for (int jj = 0; jj < 4; ++jj) {
      int n = n0 + jg * 4 + jj;
      float v = (acc[oo][jj] - mu) * isc + bb;
      v = fmaxf(v, 0.f);
      size_t oi = ((size_t)b * CH + o) * HW + n;
      out[oi] = g * v + x[oi];
    }
  }
}

// ---------------- launch ----------------
extern "C" void kernel_launch(void* const* d_in, const int* in_sizes, int n_in,
                              void* d_out, int out_size, void* d_ws, size_t ws_size,
                              hipStream_t stream) {
  const float* x    = (const float*)d_in[0];
  const float* Wq   = (const float*)d_in[1];
  const float* Wk   = (const float*)d_in[2];
  const float* Wv   = (const float*)d_in[3];
  const float* Wb1  = (const float*)d_in[4];
  const float* Wb2  = (const float*)d_in[5];
  const float* wgb  = (const float*)d_in[6];
  const float* gw1  = (const float*)d_in[7];
  const float* gb1  = (const float*)d_in[8];
  const float* gw2  = (const float*)d_in[9];
  const float* gb2  = (const float*)d_in[10];
  const float* Wo   = (const float*)d_in[11];
  const float* bns  = (const float*)d_in[12];
  const float* bnb  = (const float*)d_in[13];
  const float* bnm  = (const float*)d_in[14];
  const float* bnv  = (const float*)d_in[15];
  const float* gam  = (const float*)d_in[16];

  char* ws = (char*)d_ws;
  float* mean = (float*)(ws + OFF_MEAN);
  float* wkb  = (float*)(ws + OFF_WKB);
  bf16* qt    = (bf16*)(ws + OFF_QT);
  bf16* kt    = (bf16*)(ws + OFF_KT);
  bf16* bs1   = (bf16*)(ws + OFF_BS1);
  bf16* bs2   = (bf16*)(ws + OFF_BS2);
  bf16* vt    = (bf16*)(ws + OFF_VT);
  float* b1r  = (float*)(ws + OFF_B1R);
  float* b2r  = (float*)(ws + OFF_B2R);
  float* ctx  = (float*)(ws + OFF_CTX);
  float* pacc = (float*)(ws + OFF_PACC);
  float* pmv  = (float*)(ws + OFF_PM);
  float* plv  = (float*)(ws + OFF_PL);
  float* out  = (float*)d_out;

  hipLaunchKernelGGL(k_mean,    dim3(NB * CH),        dim3(256), 0, stream, x, mean);
  hipLaunchKernelGGL(k_gate,    dim3(NB),             dim3(256), 0, stream, mean, gw1, gb1, gw2, gb2, Wk, wkb);
  hipLaunchKernelGGL(k_proj,    dim3(NB * 128 * 2),   dim3(256), 0, stream, x, Wq, wkb, Wb1, Wb2, Wv, qt, kt, b1r, b2r, vt);
  hipLaunchKernelGGL(k_pool,    dim3(NB * HW * KC / 256), dim3(256), 0, stream, b1r, b2r, bs1, bs2);
  hipLaunchKernelGGL(k_attn,    dim3(NB * 256 * 4),   dim3(64),  0, stream, qt, kt, bs1, bs2, vt, wgb, pacc, pmv, plv);
  hipLaunchKernelGGL(k_combine, dim3(NB * HW / 4),    dim3(256), 0, stream, pacc, pmv, plv, ctx);
  hipLaunchKernelGGL(k_out,     dim3(NB * 128 * 2),   dim3(256), 0, stream, ctx, Wo, bns, bnb, bnm, bnv, gam, x, out);
}